// Round 6
// baseline (265.928 us; speedup 1.0000x reference)
//
#include <hip/hip_runtime.h>
#include <hip/hip_bf16.h>

#define NB   32
#define CIN  128
#define HH   56
#define WW   56
#define COUT 256
#define HW   3136   // 56*56
#define NCHUNK 576  // weight chunks per (b): 2 mtile * 288

typedef __bf16 bf16x8 __attribute__((ext_vector_type(8)));
typedef float floatx4 __attribute__((ext_vector_type(4)));

// ---------------- 1) FUSED: x transpose (+GAP partials) AND expert-weight swizzle ----------------
// blocks [0,3136): xpose   NCHW fp32 -> NHWC bf16, gpart partials (no atomics)
// blocks [3136,3392): wswz  convT[e][c][lane], c = mtile*288 + p*32 + cc*16 + ks*8 + mt*2 + wm
// gpart lives in d_out (scratch until conv overwrites it) to avoid aliasing wmix.
__global__ void xpose_wswz(const float* __restrict__ x, __hip_bfloat16* __restrict__ xT,
                           float* __restrict__ gpart,
                           const float* __restrict__ convs, __hip_bfloat16* __restrict__ convT) {
    __shared__ __align__(16) char smem[19008];
    int blk = blockIdx.x;
    if (blk < 3136) {
        // ---- xpose path ----
        int hwb = blk % 49; int rem = blk / 49; int ih = rem & 1; int b = rem >> 1;
        int hw0 = hwb * 64, i0 = ih * 64;
        float (*tile)[65] = (float(*)[65])smem;                 // 16640 B
        float (*red)[4]   = (float(*)[4])(smem + 16640);        // 1024 B
        const float* xp = x + ((size_t)b * CIN + i0) * HW + hw0;
        for (int t = threadIdx.x; t < 1024; t += 256) {         // float4 loads
            int ir = t >> 4, c4 = t & 15;
            float4 v = *(const float4*)(xp + (size_t)ir * HW + c4 * 4);
            tile[ir][c4 * 4 + 0] = v.x; tile[ir][c4 * 4 + 1] = v.y;
            tile[ir][c4 * 4 + 2] = v.z; tile[ir][c4 * 4 + 3] = v.w;
        }
        __syncthreads();
        __hip_bfloat16* op = xT + ((size_t)b * HW + hw0) * CIN + i0;
        for (int t = threadIdx.x; t < 512; t += 256) {
            int pp = t >> 3, seg = t & 7;
            __hip_bfloat16 tmp[8];
            #pragma unroll
            for (int j = 0; j < 8; ++j) tmp[j] = __float2bfloat16(tile[seg * 8 + j][pp]);
            *(uint4*)(op + (size_t)pp * CIN + seg * 8) = *(uint4*)tmp;
        }
        int ch = threadIdx.x & 63, grp = threadIdx.x >> 6;
        float s = 0.f;
        #pragma unroll
        for (int k = 0; k < 16; ++k) s += tile[ch][grp * 16 + k];
        red[ch][grp] = s;
        __syncthreads();
        if (threadIdx.x < 64) {
            float t4 = red[threadIdx.x][0] + red[threadIdx.x][1]
                     + red[threadIdx.x][2] + red[threadIdx.x][3];
            gpart[((size_t)b * 49 + hwb) * CIN + i0 + threadIdx.x] = t4;
        }
    } else {
        // ---- wswz path: 256 blocks = (e, mtile, wm, mt, cc, ks) ----
        int b2 = blk - 3136;
        int ks = b2 & 1, cc = (b2 >> 1) & 1, mt = (b2 >> 2) & 3;
        int wm = (b2 >> 4) & 1, mtile = (b2 >> 5) & 1, e = b2 >> 6;
        float (*tl)[297] = (float(*)[297])smem;                 // 16 x 297 x 4 = 19008 B
        int row0 = mtile * 128 + wm * 64 + mt * 16;
        const float* src = convs + (size_t)(e * COUT + row0) * 1152 + (cc * 64 + ks * 32) * 9;
        for (int i = threadIdx.x; i < 1152; i += 256) {         // 16 rows x 72 float4
            int r = i / 72, o = i - r * 72;
            float4 v = *(const float4*)(src + (size_t)r * 1152 + o * 4);
            tl[r][o * 4 + 0] = v.x; tl[r][o * 4 + 1] = v.y;
            tl[r][o * 4 + 2] = v.z; tl[r][o * 4 + 3] = v.w;
        }
        __syncthreads();
        for (int i = threadIdx.x; i < 576; i += 256) {          // 9 p-slots x 64 lanes
            int p = i >> 6, lane = i & 63;
            int col = lane & 15, quad = lane >> 4;
            int c = mtile * 288 + p * 32 + cc * 16 + ks * 8 + mt * 2 + wm;
            __hip_bfloat16 tmp[8];
            #pragma unroll
            for (int j = 0; j < 8; ++j)
                tmp[j] = __float2bfloat16(tl[col][(quad * 8 + j) * 9 + p]);
            *(uint4*)(convT + ((size_t)(e * NCHUNK + c) * 64 + lane) * 8) = *(uint4*)tmp;
        }
    }
}

// ---------------- 2) mix + router fused: per-block redundant routing (L3-resident gpart) ----------------
// 2304 blocks, 72 per b. Each block: reduce gpart -> MLP -> softmax in LDS, then mix 32B/thread.
__global__ void mix_router(const __hip_bfloat16* __restrict__ convT,
                           const float* __restrict__ gpart,
                           const float* __restrict__ w1, const float* __restrict__ b1,
                           const float* __restrict__ w2, const float* __restrict__ b2,
                           __hip_bfloat16* __restrict__ wmix) {
    __shared__ float g2[2][CIN];
    __shared__ float gs[CIN];
    __shared__ float hs[16];
    __shared__ float rr[4];
    int blk = blockIdx.x, tid = threadIdx.x;
    int b = blk / 72;
    // ---- routing (redundant per block; gpart is L2/L3-resident) ----
    {
        int ch = tid & 127, half = tid >> 7;
        float s = 0.f;
        #pragma unroll 5
        for (int h = half; h < 49; h += 2)
            s += gpart[((size_t)b * 49 + h) * CIN + ch];
        g2[half][ch] = s;
        __syncthreads();
        if (tid < CIN) gs[tid] = (g2[0][tid] + g2[1][tid]) * (1.0f / HW);
        __syncthreads();
        if (tid < 16) {
            float a = 0.f;
            #pragma unroll
            for (int i = 0; i < CIN; ++i) a += gs[i] * w1[tid * CIN + i];
            hs[tid] = fmaxf(a + b1[tid], 0.f);
        }
        __syncthreads();
        if (tid == 0) {
            float lg[4], mx = -1e30f;
            #pragma unroll
            for (int e = 0; e < 4; ++e) {
                float a = b2[e];
                #pragma unroll
                for (int r = 0; r < 16; ++r) a += hs[r] * w2[e * 16 + r];
                lg[e] = a * (1.0f / 30.0f);
                mx = fmaxf(mx, lg[e]);
            }
            float den = 0.f, ex[4];
            #pragma unroll
            for (int e = 0; e < 4; ++e) { ex[e] = expf(lg[e] - mx); den += ex[e]; }
            #pragma unroll
            for (int e = 0; e < 4; ++e) rr[e] = ex[e] / den;
        }
        __syncthreads();
    }
    float r0 = rr[0], r1 = rr[1], r2 = rr[2], r3 = rr[3];
    // ---- mix: one PAIR of chunk-lanes (32 B) per thread ----
    int t = blk * 256 + tid;
    const int PER_B = NCHUNK * 32;              // 18432 pairs per b
    int p = t - b * PER_B;                      // pair index within b (== convT pair index)
    const size_t ES = (size_t)NCHUNK * 64 * 8;  // 294912 elems per expert
    const __hip_bfloat16* sp = convT + (size_t)p * 16;
    __hip_bfloat16 o[16];
    #pragma unroll
    for (int h = 0; h < 2; ++h) {
        bf16x8 w0 = *(const bf16x8*)(sp + h * 8);
        bf16x8 w1v = *(const bf16x8*)(sp + h * 8 + ES);
        bf16x8 w2v = *(const bf16x8*)(sp + h * 8 + 2 * ES);
        bf16x8 w3v = *(const bf16x8*)(sp + h * 8 + 3 * ES);
        #pragma unroll
        for (int j = 0; j < 8; ++j) {
            float v = r0 * (float)w0[j] + r1 * (float)w1v[j]
                    + r2 * (float)w2v[j] + r3 * (float)w3v[j];
            o[h * 8 + j] = __float2bfloat16(v);
        }
    }
    uint4* d = (uint4*)(wmix + (size_t)t * 16);
    d[0] = ((uint4*)o)[0];
    d[1] = ((uint4*)o)[1];
}

// ---------------- 3) dynamic conv: 12 (cc,ks,kx) groups, 6-row bfr reuse, 3 blocks/CU ----------------
#define XSTRIDE 136   // 128 ch + 8 pad elems (16B-aligned rows)
__global__ __launch_bounds__(256, 3)
void conv_mfma(const __hip_bfloat16* __restrict__ xT,
               const __hip_bfloat16* __restrict__ wmix,
               float* __restrict__ out) {
    __shared__ __align__(16) __hip_bfloat16 xs[180 * XSTRIDE];   // 48.96 KB -> 3 blocks/CU

    // XCD-aware bijective swizzle (1792 % 8 == 0): XCD k owns 4 contiguous b's
    int lin = blockIdx.x;
    int wg  = (lin & 7) * 224 + (lin >> 3);
    int b   = wg / 56;
    int rr  = wg - b * 56;
    int mtile = rr / 28;
    int tile  = rr - mtile * 28;

    const int yt = tile >> 2, xt = tile & 3;
    const int y0 = yt * 8, x0 = xt * 16;
    const int tid = threadIdx.x;
    const int lane = tid & 63, wave = tid >> 6;
    const int wm = wave & 1, wn = wave >> 1;
    const int col = lane & 15, quad = lane >> 4;

    const __hip_bfloat16* xb = xT + (size_t)b * HW * CIN;
    const __hip_bfloat16* wptr = wmix +
        ((size_t)(b * NCHUNK + mtile * 288 + wm)) * 512 + lane * 8;

    // ---- stage full x halo tile (180 px x 128 ch) once ----
    #pragma unroll
    for (int j = 0; j < 12; ++j) {
        int tt = tid + j * 256;
        if (tt < 2880) {                       // 180 px * 16 segs
            int pix = tt >> 4, seg = tt & 15;
            int py = pix / 18, px = pix - py * 18;
            int gy = y0 - 1 + py, gx = x0 - 1 + px;
            uint4 v = {0u, 0u, 0u, 0u};
            if ((unsigned)gy < 56u && (unsigned)gx < 56u)
                v = *(const uint4*)(xb + ((size_t)(gy * 56 + gx) * CIN + seg * 8));
            *(uint4*)(&xs[pix * XSTRIDE + seg * 8]) = v;
        }
    }

    floatx4 acc[4][4];
    #pragma unroll
    for (int mt = 0; mt < 4; ++mt)
        #pragma unroll
        for (int nt = 0; nt < 4; ++nt)
            acc[mt][nt] = (floatx4){0.f, 0.f, 0.f, 0.f};

    bf16x8 af[3][4];    // weight fragments: rotating, prefetch distance 2 (u-steps)
    bf16x8 bfr[2][6];   // 6 row-fragments per (cc,ks,kx) group, double-buffered

    // u = g*3 + ky ; g = cc*6 + ks*3 + kx
    auto lda = [&](int u, bf16x8* dst) {
        const int g = u / 3, ky = u - g * 3;
        const int cc = g / 6, r6 = g - cc * 6;
        const int ks = r6 / 3, kx = r6 - ks * 3;
        const int pp = ky * 3 + kx;
        #pragma unroll
        for (int mt = 0; mt < 4; ++mt)
            dst[mt] = *(const bf16x8*)(wptr +
                (size_t)(pp * 32 + cc * 16 + ks * 8 + mt * 2) * 512);
    };
    auto ldb = [&](int g, bf16x8* dst) {
        const int cc = g / 6, r6 = g - cc * 6;
        const int ks = r6 / 3, kx = r6 - ks * 3;
        const int base = cc * 64 + ks * 32 + quad * 8;
        #pragma unroll
        for (int r = 0; r < 6; ++r)
            dst[r] = *(const bf16x8*)(&xs[((wn * 4 + r) * 18 + col + kx) * XSTRIDE + base]);
    };

    lda(0, af[0]); lda(1, af[1]);
    __syncthreads();                          // xs visible (the only barrier)
    ldb(0, bfr[0]);

    #pragma unroll
    for (int g = 0; g < 12; ++g) {
        if (g + 1 < 12) ldb(g + 1, bfr[(g + 1) & 1]);
        #pragma unroll
        for (int ky = 0; ky < 3; ++ky) {
            const int u = g * 3 + ky;
            if (u + 2 < 36) lda(u + 2, af[(u + 2) % 3]);
            __builtin_amdgcn_s_setprio(1);
            #pragma unroll
            for (int mt = 0; mt < 4; ++mt)
                #pragma unroll
                for (int nt = 0; nt < 4; ++nt)
                    acc[mt][nt] = __builtin_amdgcn_mfma_f32_16x16x32_bf16(
                        af[u % 3][mt], bfr[g & 1][nt + ky], acc[mt][nt], 0, 0, 0);
            __builtin_amdgcn_s_setprio(0);
        }
    }

    // epilogue: C/D layout col=lane&15, row=quad*4+reg
    const int x = x0 + col;
    if (x < 56) {
        #pragma unroll
        for (int mt = 0; mt < 4; ++mt) {
            int o = mtile * 128 + wm * 64 + mt * 16 + quad * 4;
            #pragma unroll
            for (int nt = 0; nt < 4; ++nt) {
                int y = y0 + wn * 4 + nt;
                float* op = out + (((size_t)b * COUT + o) * 56 + y) * 56 + x;
                #pragma unroll
                for (int r = 0; r < 4; ++r)
                    op[(size_t)r * HW] = acc[mt][nt][r];
            }
        }
    }
}

extern "C" void kernel_launch(void* const* d_in, const int* in_sizes, int n_in,
                              void* d_out, int out_size, void* d_ws, size_t ws_size,
                              hipStream_t stream) {
    const float* x     = (const float*)d_in[0];
    const float* convs = (const float*)d_in[1];
    const float* w1    = (const float*)d_in[2];
    const float* b1    = (const float*)d_in[3];
    const float* w2    = (const float*)d_in[4];
    const float* b2    = (const float*)d_in[5];
    float* out = (float*)d_out;

    char* ws = (char*)d_ws;
    __hip_bfloat16* xT   = (__hip_bfloat16*)(ws + 16896);               // 25690112 B
    __hip_bfloat16* wmix = (__hip_bfloat16*)(ws + 16896 + 25690112);    // 18874368 B
    __hip_bfloat16* convT= (__hip_bfloat16*)(ws + 16896 + 25690112 + 18874368); // 2359296 B
    // GAP partials live in d_out as scratch: written by xpose_wswz, read by
    // mix_router, then fully overwritten by conv_mfma (stream-serial => safe).
    float* gpart = out;                                                 // 802816 B used

    xpose_wswz <<<3392, 256, 0, stream>>>(x, xT, gpart, convs, convT);
    mix_router <<<2304, 256, 0, stream>>>(convT, gpart, w1, b1, w2, b2, wmix);
    conv_mfma  <<<1792, 256, 0, stream>>>(xT, wmix, out);
}

// Round 12
// 245.383 us; speedup vs baseline: 1.0837x; 1.0837x over previous
//
#include <hip/hip_runtime.h>
#include <hip/hip_bf16.h>

#define NB   32
#define CIN  128
#define HH   56
#define WW   56
#define COUT 256
#define HW   3136   // 56*56
#define NCHUNK 576  // weight chunks per (b): 2 mtile * 288

typedef __bf16 bf16x8 __attribute__((ext_vector_type(8)));
typedef float floatx4 __attribute__((ext_vector_type(4)));

// ---------------- 1) FUSED: x transpose (+GAP partials) AND expert-weight swizzle ----------------
// xpose blocks are XCD-affinity-mapped: b's blocks land on XCD b>>2 (natural xcd = blk%8),
// so xT/gpart lines are dirty in the SAME L2 that conv_mfma (same swizzle) later reads.
__global__ void xpose_wswz(const float* __restrict__ x, __hip_bfloat16* __restrict__ xT,
                           float* __restrict__ gpart,
                           const float* __restrict__ convs, __hip_bfloat16* __restrict__ convT) {
    __shared__ __align__(16) char smem[19008];
    int blk = blockIdx.x;
    if (blk < 3136) {
        // ---- xpose path: affinity decode (8 XCDs x 392 blocks; 392 = 4 b x 98) ----
        int q = blk & 7, j = blk >> 3;
        int bl = j / 98, rj = j - bl * 98;
        int b = q * 4 + bl;
        int ih = rj / 49, hwb = rj - ih * 49;
        int hw0 = hwb * 64, i0 = ih * 64;
        float (*tile)[65] = (float(*)[65])smem;                 // 16640 B
        float (*red)[4]   = (float(*)[4])(smem + 16640);        // 1024 B
        const float* xp = x + ((size_t)b * CIN + i0) * HW + hw0;
        for (int t = threadIdx.x; t < 1024; t += 256) {         // float4 loads
            int ir = t >> 4, c4 = t & 15;
            float4 v = *(const float4*)(xp + (size_t)ir * HW + c4 * 4);
            tile[ir][c4 * 4 + 0] = v.x; tile[ir][c4 * 4 + 1] = v.y;
            tile[ir][c4 * 4 + 2] = v.z; tile[ir][c4 * 4 + 3] = v.w;
        }
        __syncthreads();
        __hip_bfloat16* op = xT + ((size_t)b * HW + hw0) * CIN + i0;
        for (int t = threadIdx.x; t < 512; t += 256) {
            int pp = t >> 3, seg = t & 7;
            __hip_bfloat16 tmp[8];
            #pragma unroll
            for (int jj = 0; jj < 8; ++jj) tmp[jj] = __float2bfloat16(tile[seg * 8 + jj][pp]);
            *(uint4*)(op + (size_t)pp * CIN + seg * 8) = *(uint4*)tmp;
        }
        int ch = threadIdx.x & 63, grp = threadIdx.x >> 6;
        float s = 0.f;
        #pragma unroll
        for (int k = 0; k < 16; ++k) s += tile[ch][grp * 16 + k];
        red[ch][grp] = s;
        __syncthreads();
        if (threadIdx.x < 64) {
            float t4 = red[threadIdx.x][0] + red[threadIdx.x][1]
                     + red[threadIdx.x][2] + red[threadIdx.x][3];
            gpart[((size_t)b * 49 + hwb) * CIN + i0 + threadIdx.x] = t4;
        }
    } else {
        // ---- wswz path: 256 blocks = (e, mtile, wm, mt, cc, ks); convT read by all XCDs ----
        int b2 = blk - 3136;
        int ks = b2 & 1, cc = (b2 >> 1) & 1, mt = (b2 >> 2) & 3;
        int wm = (b2 >> 4) & 1, mtile = (b2 >> 5) & 1, e = b2 >> 6;
        float (*tl)[297] = (float(*)[297])smem;                 // 16 x 297 x 4 = 19008 B
        int row0 = mtile * 128 + wm * 64 + mt * 16;
        const float* src = convs + (size_t)(e * COUT + row0) * 1152 + (cc * 64 + ks * 32) * 9;
        for (int i = threadIdx.x; i < 1152; i += 256) {         // 16 rows x 72 float4
            int r = i / 72, o = i - r * 72;
            float4 v = *(const float4*)(src + (size_t)r * 1152 + o * 4);
            tl[r][o * 4 + 0] = v.x; tl[r][o * 4 + 1] = v.y;
            tl[r][o * 4 + 2] = v.z; tl[r][o * 4 + 3] = v.w;
        }
        __syncthreads();
        for (int i = threadIdx.x; i < 576; i += 256) {          // 9 p-slots x 64 lanes
            int p = i >> 6, lane = i & 63;
            int col = lane & 15, quad = lane >> 4;
            int c = mtile * 288 + p * 32 + cc * 16 + ks * 8 + mt * 2 + wm;
            __hip_bfloat16 tmp[8];
            #pragma unroll
            for (int jj = 0; jj < 8; ++jj)
                tmp[jj] = __float2bfloat16(tl[col][(quad * 8 + jj) * 9 + p]);
            *(uint4*)(convT + ((size_t)(e * NCHUNK + c) * 64 + lane) * 8) = *(uint4*)tmp;
        }
    }
}

// ---------------- 2) router: reduce GAP partials + MLP + softmax(logits/30) ----------------
// affinity: block for b runs on XCD b>>2 (local gpart reads)
__global__ void router_kernel(const float* __restrict__ gpart,
                              const float* __restrict__ w1, const float* __restrict__ b1,
                              const float* __restrict__ w2, const float* __restrict__ b2,
                              float* __restrict__ routing) {
    int blk = blockIdx.x;
    int b = (blk & 7) * 4 + (blk >> 3);            // 32 blocks x 128 threads
    int ch = threadIdx.x;
    __shared__ float gs[CIN];
    __shared__ float hs[16];
    float s = 0.f;
    #pragma unroll 7
    for (int hwb = 0; hwb < 49; ++hwb)
        s += gpart[((size_t)b * 49 + hwb) * CIN + ch];
    gs[ch] = s * (1.0f / HW);
    __syncthreads();
    if (ch < 16) {
        float a = 0.f;
        #pragma unroll
        for (int i = 0; i < CIN; ++i) a += gs[i] * w1[ch * CIN + i];
        hs[ch] = fmaxf(a + b1[ch], 0.f);
    }
    __syncthreads();
    if (ch == 0) {
        float lg[4], mx = -1e30f;
        #pragma unroll
        for (int e = 0; e < 4; ++e) {
            float a = b2[e];
            #pragma unroll
            for (int r = 0; r < 16; ++r) a += hs[r] * w2[e * 16 + r];
            lg[e] = a * (1.0f / 30.0f);
            mx = fmaxf(mx, lg[e]);
        }
        float den = 0.f, ex[4];
        #pragma unroll
        for (int e = 0; e < 4; ++e) { ex[e] = expf(lg[e] - mx); den += ex[e]; }
        #pragma unroll
        for (int e = 0; e < 4; ++e) routing[b * 4 + e] = ex[e] / den;
    }
}

// ---------------- 3) mix: wmix[b][c][lane] = sum_e r[b][e] * convT[e][c][lane] (32B/thread) ----------------
// affinity: b's 72 blocks run on XCD b>>2, so wmix lines are local-dirty for conv_mfma.
__global__ void mix_kernel(const __hip_bfloat16* __restrict__ convT,
                           const float* __restrict__ routing,
                           __hip_bfloat16* __restrict__ wmix) {
    int blk = blockIdx.x, tid = threadIdx.x;       // 2304 blocks
    int q = blk & 7, j = blk >> 3;                 // j < 288 = 4 b x 72
    int bl = j / 72;
    int b = q * 4 + bl;
    int jj = j - bl * 72;
    int pair = jj * 256 + tid;                     // [0, 18432) pairs within b
    float r0 = routing[b * 4 + 0], r1 = routing[b * 4 + 1];
    float r2 = routing[b * 4 + 2], r3 = routing[b * 4 + 3];
    const size_t ES = (size_t)NCHUNK * 64 * 8;     // 294912 elems per expert
    const __hip_bfloat16* sp = convT + (size_t)pair * 16;
    __hip_bfloat16 o[16];
    #pragma unroll
    for (int h = 0; h < 2; ++h) {
        bf16x8 w0 = *(const bf16x8*)(sp + h * 8);
        bf16x8 w1v = *(const bf16x8*)(sp + h * 8 + ES);
        bf16x8 w2v = *(const bf16x8*)(sp + h * 8 + 2 * ES);
        bf16x8 w3v = *(const bf16x8*)(sp + h * 8 + 3 * ES);
        #pragma unroll
        for (int k = 0; k < 8; ++k) {
            float v = r0 * (float)w0[k] + r1 * (float)w1v[k]
                    + r2 * (float)w2v[k] + r3 * (float)w3v[k];
            o[h * 8 + k] = __float2bfloat16(v);
        }
    }
    uint4* d = (uint4*)(wmix + ((size_t)b * 18432 + pair) * 16);
    d[0] = ((uint4*)o)[0];
    d[1] = ((uint4*)o)[1];
}

// ---------------- 4) dynamic conv: measured-best config (r2: 64.5us) + nontemporal epilogue ----------------
#define XSTRIDE 136   // 128 ch + 8 pad elems (16B-aligned rows)
__global__ __launch_bounds__(256, 2)
void conv_mfma(const __hip_bfloat16* __restrict__ xT,
               const __hip_bfloat16* __restrict__ wmix,
               float* __restrict__ out) {
    __shared__ __align__(16) __hip_bfloat16 xs[180 * XSTRIDE];   // 48.96 KB

    // XCD-aware bijective swizzle (1792 % 8 == 0): XCD k owns 4 contiguous b's
    int lin = blockIdx.x;
    int wg  = (lin & 7) * 224 + (lin >> 3);
    int b   = wg / 56;
    int rr  = wg - b * 56;
    int mtile = rr / 28;
    int tile  = rr - mtile * 28;

    const int yt = tile >> 2, xt = tile & 3;
    const int y0 = yt * 8, x0 = xt * 16;
    const int tid = threadIdx.x;
    const int lane = tid & 63, wave = tid >> 6;
    const int wm = wave & 1, wn = wave >> 1;
    const int col = lane & 15, quad = lane >> 4;

    const __hip_bfloat16* xb = xT + (size_t)b * HW * CIN;
    const __hip_bfloat16* wptr = wmix +
        ((size_t)(b * NCHUNK + mtile * 288 + wm)) * 512 + lane * 8;

    // ---- stage full x halo tile (180 px x 128 ch) once ----
    #pragma unroll
    for (int j = 0; j < 12; ++j) {
        int tt = tid + j * 256;
        if (tt < 2880) {                       // 180 px * 16 segs
            int pix = tt >> 4, seg = tt & 15;
            int py = pix / 18, px = pix - py * 18;
            int gy = y0 - 1 + py, gx = x0 - 1 + px;
            uint4 v = {0u, 0u, 0u, 0u};
            if ((unsigned)gy < 56u && (unsigned)gx < 56u)
                v = *(const uint4*)(xb + ((size_t)(gy * 56 + gx) * CIN + seg * 8));
            *(uint4*)(&xs[pix * XSTRIDE + seg * 8]) = v;
        }
    }

    floatx4 acc[4][4];
    #pragma unroll
    for (int mt = 0; mt < 4; ++mt)
        #pragma unroll
        for (int nt = 0; nt < 4; ++nt)
            acc[mt][nt] = (floatx4){0.f, 0.f, 0.f, 0.f};

    bf16x8 af[4][4];    // weight fragments: rotating, prefetch distance 3
    bf16x8 bfr[2][6];   // 6 row-fragments per (cc,ks,kx) group, double-buffered

    // u = g*3 + ky ; g = cc*6 + ks*3 + kx
    auto lda = [&](int u, bf16x8* dst) {
        const int g = u / 3, ky = u - g * 3;
        const int cc = g / 6, r6 = g - cc * 6;
        const int ks = r6 / 3, kx = r6 - ks * 3;
        const int pp = ky * 3 + kx;
        #pragma unroll
        for (int mt = 0; mt < 4; ++mt)
            dst[mt] = *(const bf16x8*)(wptr +
                (size_t)(pp * 32 + cc * 16 + ks * 8 + mt * 2) * 512);
    };
    auto ldb = [&](int g, bf16x8* dst) {
        const int cc = g / 6, r6 = g - cc * 6;
        const int ks = r6 / 3, kx = r6 - ks * 3;
        const int base = cc * 64 + ks * 32 + quad * 8;
        #pragma unroll
        for (int r = 0; r < 6; ++r)
            dst[r] = *(const bf16x8*)(&xs[((wn * 4 + r) * 18 + col + kx) * XSTRIDE + base]);
    };

    lda(0, af[0]); lda(1, af[1]); lda(2, af[2]);
    __syncthreads();                          // xs visible (the only barrier)
    ldb(0, bfr[0]);

    #pragma unroll
    for (int g = 0; g < 12; ++g) {
        if (g + 1 < 12) ldb(g + 1, bfr[(g + 1) & 1]);
        #pragma unroll
        for (int ky = 0; ky < 3; ++ky) {
            const int u = g * 3 + ky;
            if (u + 3 < 36) lda(u + 3, af[(u + 3) & 3]);
            __builtin_amdgcn_s_setprio(1);
            #pragma unroll
            for (int mt = 0; mt < 4; ++mt)
                #pragma unroll
                for (int nt = 0; nt < 4; ++nt)
                    acc[mt][nt] = __builtin_amdgcn_mfma_f32_16x16x32_bf16(
                        af[u & 3][mt], bfr[g & 1][nt + ky], acc[mt][nt], 0, 0, 0);
            __builtin_amdgcn_s_setprio(0);
        }
    }

    // epilogue: C/D layout col=lane&15, row=quad*4+reg; nontemporal (out never re-read,
    // keeps 102 MB of write traffic from evicting wmix/xT out of L2)
    const int x = x0 + col;
    if (x < 56) {
        #pragma unroll
        for (int mt = 0; mt < 4; ++mt) {
            int o = mtile * 128 + wm * 64 + mt * 16 + quad * 4;
            #pragma unroll
            for (int nt = 0; nt < 4; ++nt) {
                int y = y0 + wn * 4 + nt;
                float* op = out + (((size_t)b * COUT + o) * 56 + y) * 56 + x;
                #pragma unroll
                for (int r = 0; r < 4; ++r)
                    __builtin_nontemporal_store(acc[mt][nt][r], op + (size_t)r * HW);
            }
        }
    }
}

extern "C" void kernel_launch(void* const* d_in, const int* in_sizes, int n_in,
                              void* d_out, int out_size, void* d_ws, size_t ws_size,
                              hipStream_t stream) {
    const float* x     = (const float*)d_in[0];
    const float* convs = (const float*)d_in[1];
    const float* w1    = (const float*)d_in[2];
    const float* b1    = (const float*)d_in[3];
    const float* w2    = (const float*)d_in[4];
    const float* b2    = (const float*)d_in[5];
    float* out = (float*)d_out;

    char* ws = (char*)d_ws;
    float* routing       = (float*)(ws + 16384);                        // 512 B
    __hip_bfloat16* xT   = (__hip_bfloat16*)(ws + 16896);               // 25690112 B
    __hip_bfloat16* wmix = (__hip_bfloat16*)(ws + 16896 + 25690112);    // 18874368 B
    __hip_bfloat16* convT= (__hip_bfloat16*)(ws + 16896 + 25690112 + 18874368); // 2359296 B
    // GAP partials alias the wmix region: written by xpose_wswz, read by router,
    // and only then is wmix produced by mix_kernel (stream-serial => safe).
    float* gpart = (float*)wmix;                                        // 802816 B used

    xpose_wswz   <<<3392, 256, 0, stream>>>(x, xT, gpart, convs, convT);
    router_kernel<<<32, 128, 0, stream>>>(gpart, w1, b1, w2, b2, routing);
    mix_kernel   <<<2304, 256, 0, stream>>>(convT, routing, wmix);
    conv_mfma    <<<1792, 256, 0, stream>>>(xT, wmix, out);
}

// Round 13
// 214.278 us; speedup vs baseline: 1.2410x; 1.1452x over previous
//
#include <hip/hip_runtime.h>
#include <hip/hip_bf16.h>

#define NB   32
#define CIN  128
#define HH   56
#define WW   56
#define COUT 256
#define HW   3136   // 56*56
#define NCHUNK 576  // weight chunks per (b): 2 mtile * 288

typedef __bf16 bf16x8 __attribute__((ext_vector_type(8)));
typedef float floatx4 __attribute__((ext_vector_type(4)));

// ---------------- 1) FUSED: x transpose (+GAP partials) AND expert-weight swizzle ----------------
// xpose blocks are XCD-affinity-mapped: b's blocks land on XCD b>>2 (natural xcd = blk%8),
// so xT/gpart lines are dirty in the SAME L2 that conv_mfma (same swizzle) later reads.
__global__ void xpose_wswz(const float* __restrict__ x, __hip_bfloat16* __restrict__ xT,
                           float* __restrict__ gpart,
                           const float* __restrict__ convs, __hip_bfloat16* __restrict__ convT) {
    __shared__ __align__(16) char smem[19008];
    int blk = blockIdx.x;
    if (blk < 3136) {
        // ---- xpose path: affinity decode (8 XCDs x 392 blocks; 392 = 4 b x 98) ----
        int q = blk & 7, j = blk >> 3;
        int bl = j / 98, rj = j - bl * 98;
        int b = q * 4 + bl;
        int ih = rj / 49, hwb = rj - ih * 49;
        int hw0 = hwb * 64, i0 = ih * 64;
        float (*tile)[65] = (float(*)[65])smem;                 // 16640 B
        float (*red)[4]   = (float(*)[4])(smem + 16640);        // 1024 B
        const float* xp = x + ((size_t)b * CIN + i0) * HW + hw0;
        for (int t = threadIdx.x; t < 1024; t += 256) {         // float4 loads
            int ir = t >> 4, c4 = t & 15;
            float4 v = *(const float4*)(xp + (size_t)ir * HW + c4 * 4);
            tile[ir][c4 * 4 + 0] = v.x; tile[ir][c4 * 4 + 1] = v.y;
            tile[ir][c4 * 4 + 2] = v.z; tile[ir][c4 * 4 + 3] = v.w;
        }
        __syncthreads();
        __hip_bfloat16* op = xT + ((size_t)b * HW + hw0) * CIN + i0;
        for (int t = threadIdx.x; t < 512; t += 256) {
            int pp = t >> 3, seg = t & 7;
            __hip_bfloat16 tmp[8];
            #pragma unroll
            for (int jj = 0; jj < 8; ++jj) tmp[jj] = __float2bfloat16(tile[seg * 8 + jj][pp]);
            *(uint4*)(op + (size_t)pp * CIN + seg * 8) = *(uint4*)tmp;
        }
        int ch = threadIdx.x & 63, grp = threadIdx.x >> 6;
        float s = 0.f;
        #pragma unroll
        for (int k = 0; k < 16; ++k) s += tile[ch][grp * 16 + k];
        red[ch][grp] = s;
        __syncthreads();
        if (threadIdx.x < 64) {
            float t4 = red[threadIdx.x][0] + red[threadIdx.x][1]
                     + red[threadIdx.x][2] + red[threadIdx.x][3];
            gpart[((size_t)b * 49 + hwb) * CIN + i0 + threadIdx.x] = t4;
        }
    } else {
        // ---- wswz path: 256 blocks = (e, mtile, wm, mt, cc, ks); convT read by all XCDs ----
        int b2 = blk - 3136;
        int ks = b2 & 1, cc = (b2 >> 1) & 1, mt = (b2 >> 2) & 3;
        int wm = (b2 >> 4) & 1, mtile = (b2 >> 5) & 1, e = b2 >> 6;
        float (*tl)[297] = (float(*)[297])smem;                 // 16 x 297 x 4 = 19008 B
        int row0 = mtile * 128 + wm * 64 + mt * 16;
        const float* src = convs + (size_t)(e * COUT + row0) * 1152 + (cc * 64 + ks * 32) * 9;
        for (int i = threadIdx.x; i < 1152; i += 256) {         // 16 rows x 72 float4
            int r = i / 72, o = i - r * 72;
            float4 v = *(const float4*)(src + (size_t)r * 1152 + o * 4);
            tl[r][o * 4 + 0] = v.x; tl[r][o * 4 + 1] = v.y;
            tl[r][o * 4 + 2] = v.z; tl[r][o * 4 + 3] = v.w;
        }
        __syncthreads();
        for (int i = threadIdx.x; i < 576; i += 256) {          // 9 p-slots x 64 lanes
            int p = i >> 6, lane = i & 63;
            int col = lane & 15, quad = lane >> 4;
            int c = mtile * 288 + p * 32 + cc * 16 + ks * 8 + mt * 2 + wm;
            __hip_bfloat16 tmp[8];
            #pragma unroll
            for (int jj = 0; jj < 8; ++jj)
                tmp[jj] = __float2bfloat16(tl[col][(quad * 8 + jj) * 9 + p]);
            *(uint4*)(convT + ((size_t)(e * NCHUNK + c) * 64 + lane) * 8) = *(uint4*)tmp;
        }
    }
}

// ---------------- 2) router: reduce GAP partials + MLP + softmax(logits/30) ----------------
// affinity: block for b runs on XCD b>>2 (local gpart reads)
__global__ void router_kernel(const float* __restrict__ gpart,
                              const float* __restrict__ w1, const float* __restrict__ b1,
                              const float* __restrict__ w2, const float* __restrict__ b2,
                              float* __restrict__ routing) {
    int blk = blockIdx.x;
    int b = (blk & 7) * 4 + (blk >> 3);            // 32 blocks x 128 threads
    int ch = threadIdx.x;
    __shared__ float gs[CIN];
    __shared__ float hs[16];
    float s = 0.f;
    #pragma unroll 7
    for (int hwb = 0; hwb < 49; ++hwb)
        s += gpart[((size_t)b * 49 + hwb) * CIN + ch];
    gs[ch] = s * (1.0f / HW);
    __syncthreads();
    if (ch < 16) {
        float a = 0.f;
        #pragma unroll
        for (int i = 0; i < CIN; ++i) a += gs[i] * w1[ch * CIN + i];
        hs[ch] = fmaxf(a + b1[ch], 0.f);
    }
    __syncthreads();
    if (ch == 0) {
        float lg[4], mx = -1e30f;
        #pragma unroll
        for (int e = 0; e < 4; ++e) {
            float a = b2[e];
            #pragma unroll
            for (int r = 0; r < 16; ++r) a += hs[r] * w2[e * 16 + r];
            lg[e] = a * (1.0f / 30.0f);
            mx = fmaxf(mx, lg[e]);
        }
        float den = 0.f, ex[4];
        #pragma unroll
        for (int e = 0; e < 4; ++e) { ex[e] = expf(lg[e] - mx); den += ex[e]; }
        #pragma unroll
        for (int e = 0; e < 4; ++e) routing[b * 4 + e] = ex[e] / den;
    }
}

// ---------------- 3) mix: wmix[b][c][lane] = sum_e r[b][e] * convT[e][c][lane] (32B/thread) ----------------
// affinity: b's 72 blocks run on XCD b>>2, so wmix lines are local-dirty for conv_mfma.
__global__ void mix_kernel(const __hip_bfloat16* __restrict__ convT,
                           const float* __restrict__ routing,
                           __hip_bfloat16* __restrict__ wmix) {
    int blk = blockIdx.x, tid = threadIdx.x;       // 2304 blocks
    int q = blk & 7, j = blk >> 3;                 // j < 288 = 4 b x 72
    int bl = j / 72;
    int b = q * 4 + bl;
    int jj = j - bl * 72;
    int pair = jj * 256 + tid;                     // [0, 18432) pairs within b
    float r0 = routing[b * 4 + 0], r1 = routing[b * 4 + 1];
    float r2 = routing[b * 4 + 2], r3 = routing[b * 4 + 3];
    const size_t ES = (size_t)NCHUNK * 64 * 8;     // 294912 elems per expert
    const __hip_bfloat16* sp = convT + (size_t)pair * 16;
    __hip_bfloat16 o[16];
    #pragma unroll
    for (int h = 0; h < 2; ++h) {
        bf16x8 w0 = *(const bf16x8*)(sp + h * 8);
        bf16x8 w1v = *(const bf16x8*)(sp + h * 8 + ES);
        bf16x8 w2v = *(const bf16x8*)(sp + h * 8 + 2 * ES);
        bf16x8 w3v = *(const bf16x8*)(sp + h * 8 + 3 * ES);
        #pragma unroll
        for (int k = 0; k < 8; ++k) {
            float v = r0 * (float)w0[k] + r1 * (float)w1v[k]
                    + r2 * (float)w2v[k] + r3 * (float)w3v[k];
            o[h * 8 + k] = __float2bfloat16(v);
        }
    }
    uint4* d = (uint4*)(wmix + ((size_t)b * 18432 + pair) * 16);
    d[0] = ((uint4*)o)[0];
    d[1] = ((uint4*)o)[1];
}

// ---------------- 4) dynamic conv: r2 measured-best config; plain epilogue stores ----------------
#define XSTRIDE 136   // 128 ch + 8 pad elems (16B-aligned rows)
__global__ __launch_bounds__(256, 2)
void conv_mfma(const __hip_bfloat16* __restrict__ xT,
               const __hip_bfloat16* __restrict__ wmix,
               float* __restrict__ out) {
    __shared__ __align__(16) __hip_bfloat16 xs[180 * XSTRIDE];   // 48.96 KB

    // XCD-aware bijective swizzle (1792 % 8 == 0): XCD k owns 4 contiguous b's
    int lin = blockIdx.x;
    int wg  = (lin & 7) * 224 + (lin >> 3);
    int b   = wg / 56;
    int rr  = wg - b * 56;
    int mtile = rr / 28;
    int tile  = rr - mtile * 28;

    const int yt = tile >> 2, xt = tile & 3;
    const int y0 = yt * 8, x0 = xt * 16;
    const int tid = threadIdx.x;
    const int lane = tid & 63, wave = tid >> 6;
    const int wm = wave & 1, wn = wave >> 1;
    const int col = lane & 15, quad = lane >> 4;

    const __hip_bfloat16* xb = xT + (size_t)b * HW * CIN;
    const __hip_bfloat16* wptr = wmix +
        ((size_t)(b * NCHUNK + mtile * 288 + wm)) * 512 + lane * 8;

    // ---- stage full x halo tile (180 px x 128 ch) once ----
    #pragma unroll
    for (int j = 0; j < 12; ++j) {
        int tt = tid + j * 256;
        if (tt < 2880) {                       // 180 px * 16 segs
            int pix = tt >> 4, seg = tt & 15;
            int py = pix / 18, px = pix - py * 18;
            int gy = y0 - 1 + py, gx = x0 - 1 + px;
            uint4 v = {0u, 0u, 0u, 0u};
            if ((unsigned)gy < 56u && (unsigned)gx < 56u)
                v = *(const uint4*)(xb + ((size_t)(gy * 56 + gx) * CIN + seg * 8));
            *(uint4*)(&xs[pix * XSTRIDE + seg * 8]) = v;
        }
    }

    floatx4 acc[4][4];
    #pragma unroll
    for (int mt = 0; mt < 4; ++mt)
        #pragma unroll
        for (int nt = 0; nt < 4; ++nt)
            acc[mt][nt] = (floatx4){0.f, 0.f, 0.f, 0.f};

    bf16x8 af[4][4];    // weight fragments: rotating, prefetch distance 3
    bf16x8 bfr[2][6];   // 6 row-fragments per (cc,ks,kx) group, double-buffered

    // u = g*3 + ky ; g = cc*6 + ks*3 + kx
    auto lda = [&](int u, bf16x8* dst) {
        const int g = u / 3, ky = u - g * 3;
        const int cc = g / 6, r6 = g - cc * 6;
        const int ks = r6 / 3, kx = r6 - ks * 3;
        const int pp = ky * 3 + kx;
        #pragma unroll
        for (int mt = 0; mt < 4; ++mt)
            dst[mt] = *(const bf16x8*)(wptr +
                (size_t)(pp * 32 + cc * 16 + ks * 8 + mt * 2) * 512);
    };
    auto ldb = [&](int g, bf16x8* dst) {
        const int cc = g / 6, r6 = g - cc * 6;
        const int ks = r6 / 3, kx = r6 - ks * 3;
        const int base = cc * 64 + ks * 32 + quad * 8;
        #pragma unroll
        for (int r = 0; r < 6; ++r)
            dst[r] = *(const bf16x8*)(&xs[((wn * 4 + r) * 18 + col + kx) * XSTRIDE + base]);
    };

    lda(0, af[0]); lda(1, af[1]); lda(2, af[2]);
    __syncthreads();                          // xs visible (the only barrier)
    ldb(0, bfr[0]);

    #pragma unroll
    for (int g = 0; g < 12; ++g) {
        if (g + 1 < 12) ldb(g + 1, bfr[(g + 1) & 1]);
        #pragma unroll
        for (int ky = 0; ky < 3; ++ky) {
            const int u = g * 3 + ky;
            if (u + 3 < 36) lda(u + 3, af[(u + 3) & 3]);
            __builtin_amdgcn_s_setprio(1);
            #pragma unroll
            for (int mt = 0; mt < 4; ++mt)
                #pragma unroll
                for (int nt = 0; nt < 4; ++nt)
                    acc[mt][nt] = __builtin_amdgcn_mfma_f32_16x16x32_bf16(
                        af[u & 3][mt], bfr[g & 1][nt + ky], acc[mt][nt], 0, 0, 0);
            __builtin_amdgcn_s_setprio(0);
        }
    }

    // epilogue: C/D layout col=lane&15, row=quad*4+reg; PLAIN stores (r12 lesson:
    // nontemporal scalar stores defeat L2 write-combining: WRITE 102->134MB, conv +43us)
    const int x = x0 + col;
    if (x < 56) {
        #pragma unroll
        for (int mt = 0; mt < 4; ++mt) {
            int o = mtile * 128 + wm * 64 + mt * 16 + quad * 4;
            #pragma unroll
            for (int nt = 0; nt < 4; ++nt) {
                int y = y0 + wn * 4 + nt;
                float* op = out + (((size_t)b * COUT + o) * 56 + y) * 56 + x;
                #pragma unroll
                for (int r = 0; r < 4; ++r)
                    op[(size_t)r * HW] = acc[mt][nt][r];
            }
        }
    }
}

extern "C" void kernel_launch(void* const* d_in, const int* in_sizes, int n_in,
                              void* d_out, int out_size, void* d_ws, size_t ws_size,
                              hipStream_t stream) {
    const float* x     = (const float*)d_in[0];
    const float* convs = (const float*)d_in[1];
    const float* w1    = (const float*)d_in[2];
    const float* b1    = (const float*)d_in[3];
    const float* w2    = (const float*)d_in[4];
    const float* b2    = (const float*)d_in[5];
    float* out = (float*)d_out;

    char* ws = (char*)d_ws;
    float* routing       = (float*)(ws + 16384);                        // 512 B
    __hip_bfloat16* xT   = (__hip_bfloat16*)(ws + 16896);               // 25690112 B
    __hip_bfloat16* wmix = (__hip_bfloat16*)(ws + 16896 + 25690112);    // 18874368 B
    __hip_bfloat16* convT= (__hip_bfloat16*)(ws + 16896 + 25690112 + 18874368); // 2359296 B
    // GAP partials alias the wmix region: written by xpose_wswz, read by router,
    // and only then is wmix produced by mix_kernel (stream-serial => safe).
    float* gpart = (float*)wmix;                                        // 802816 B used

    xpose_wswz   <<<3392, 256, 0, stream>>>(x, xT, gpart, convs, convT);
    router_kernel<<<32, 128, 0, stream>>>(gpart, w1, b1, w2, b2, routing);
    mix_kernel   <<<2304, 256, 0, stream>>>(convT, routing, wmix);
    conv_mfma    <<<1792, 256, 0, stream>>>(xT, wmix, out);
}

// Round 14
// 210.354 us; speedup vs baseline: 1.2642x; 1.0187x over previous
//
#include <hip/hip_runtime.h>
#include <hip/hip_bf16.h>

#define NB   32
#define CIN  128
#define HH   56
#define WW   56
#define COUT 256
#define HW   3136   // 56*56
#define NCHUNK 576  // weight chunks per (b): 2 mtile * 288

typedef __bf16 bf16x8 __attribute__((ext_vector_type(8)));
typedef float floatx4 __attribute__((ext_vector_type(4)));

// ---------------- 1) FUSED: x transpose (+GAP partials) AND expert-weight swizzle ----------------
// xpose blocks are XCD-affinity-mapped: b's blocks land on XCD b>>2 (natural xcd = blk%8),
// so xT/gpart lines are dirty in the SAME L2 that conv_mfma (same swizzle) later reads.
__global__ void xpose_wswz(const float* __restrict__ x, __hip_bfloat16* __restrict__ xT,
                           float* __restrict__ gpart,
                           const float* __restrict__ convs, __hip_bfloat16* __restrict__ convT) {
    __shared__ __align__(16) char smem[19008];
    int blk = blockIdx.x;
    if (blk < 3136) {
        // ---- xpose path: affinity decode (8 XCDs x 392 blocks; 392 = 4 b x 98) ----
        int q = blk & 7, j = blk >> 3;
        int bl = j / 98, rj = j - bl * 98;
        int b = q * 4 + bl;
        int ih = rj / 49, hwb = rj - ih * 49;
        int hw0 = hwb * 64, i0 = ih * 64;
        float (*tile)[65] = (float(*)[65])smem;                 // 16640 B
        float (*red)[4]   = (float(*)[4])(smem + 16640);        // 1024 B
        const float* xp = x + ((size_t)b * CIN + i0) * HW + hw0;
        for (int t = threadIdx.x; t < 1024; t += 256) {         // float4 loads
            int ir = t >> 4, c4 = t & 15;
            float4 v = *(const float4*)(xp + (size_t)ir * HW + c4 * 4);
            tile[ir][c4 * 4 + 0] = v.x; tile[ir][c4 * 4 + 1] = v.y;
            tile[ir][c4 * 4 + 2] = v.z; tile[ir][c4 * 4 + 3] = v.w;
        }
        __syncthreads();
        __hip_bfloat16* op = xT + ((size_t)b * HW + hw0) * CIN + i0;
        for (int t = threadIdx.x; t < 512; t += 256) {
            int pp = t >> 3, seg = t & 7;
            __hip_bfloat16 tmp[8];
            #pragma unroll
            for (int jj = 0; jj < 8; ++jj) tmp[jj] = __float2bfloat16(tile[seg * 8 + jj][pp]);
            *(uint4*)(op + (size_t)pp * CIN + seg * 8) = *(uint4*)tmp;
        }
        int ch = threadIdx.x & 63, grp = threadIdx.x >> 6;
        float s = 0.f;
        #pragma unroll
        for (int k = 0; k < 16; ++k) s += tile[ch][grp * 16 + k];
        red[ch][grp] = s;
        __syncthreads();
        if (threadIdx.x < 64) {
            float t4 = red[threadIdx.x][0] + red[threadIdx.x][1]
                     + red[threadIdx.x][2] + red[threadIdx.x][3];
            gpart[((size_t)b * 49 + hwb) * CIN + i0 + threadIdx.x] = t4;
        }
    } else {
        // ---- wswz path: 256 blocks = (e, mtile, wm, mt, cc, ks); convT read by all XCDs ----
        int b2 = blk - 3136;
        int ks = b2 & 1, cc = (b2 >> 1) & 1, mt = (b2 >> 2) & 3;
        int wm = (b2 >> 4) & 1, mtile = (b2 >> 5) & 1, e = b2 >> 6;
        float (*tl)[297] = (float(*)[297])smem;                 // 16 x 297 x 4 = 19008 B
        int row0 = mtile * 128 + wm * 64 + mt * 16;
        const float* src = convs + (size_t)(e * COUT + row0) * 1152 + (cc * 64 + ks * 32) * 9;
        for (int i = threadIdx.x; i < 1152; i += 256) {         // 16 rows x 72 float4
            int r = i / 72, o = i - r * 72;
            float4 v = *(const float4*)(src + (size_t)r * 1152 + o * 4);
            tl[r][o * 4 + 0] = v.x; tl[r][o * 4 + 1] = v.y;
            tl[r][o * 4 + 2] = v.z; tl[r][o * 4 + 3] = v.w;
        }
        __syncthreads();
        for (int i = threadIdx.x; i < 576; i += 256) {          // 9 p-slots x 64 lanes
            int p = i >> 6, lane = i & 63;
            int col = lane & 15, quad = lane >> 4;
            int c = mtile * 288 + p * 32 + cc * 16 + ks * 8 + mt * 2 + wm;
            __hip_bfloat16 tmp[8];
            #pragma unroll
            for (int jj = 0; jj < 8; ++jj)
                tmp[jj] = __float2bfloat16(tl[col][(quad * 8 + jj) * 9 + p]);
            *(uint4*)(convT + ((size_t)(e * NCHUNK + c) * 64 + lane) * 8) = *(uint4*)tmp;
        }
    }
}

// ---------------- 2) router: reduce GAP partials + MLP + softmax(logits/30) ----------------
// affinity: block for b runs on XCD b>>2 (local gpart reads)
__global__ void router_kernel(const float* __restrict__ gpart,
                              const float* __restrict__ w1, const float* __restrict__ b1,
                              const float* __restrict__ w2, const float* __restrict__ b2,
                              float* __restrict__ routing) {
    int blk = blockIdx.x;
    int b = (blk & 7) * 4 + (blk >> 3);            // 32 blocks x 128 threads
    int ch = threadIdx.x;
    __shared__ float gs[CIN];
    __shared__ float hs[16];
    float s = 0.f;
    #pragma unroll 7
    for (int hwb = 0; hwb < 49; ++hwb)
        s += gpart[((size_t)b * 49 + hwb) * CIN + ch];
    gs[ch] = s * (1.0f / HW);
    __syncthreads();
    if (ch < 16) {
        float a = 0.f;
        #pragma unroll
        for (int i = 0; i < CIN; ++i) a += gs[i] * w1[ch * CIN + i];
        hs[ch] = fmaxf(a + b1[ch], 0.f);
    }
    __syncthreads();
    if (ch == 0) {
        float lg[4], mx = -1e30f;
        #pragma unroll
        for (int e = 0; e < 4; ++e) {
            float a = b2[e];
            #pragma unroll
            for (int r = 0; r < 16; ++r) a += hs[r] * w2[e * 16 + r];
            lg[e] = a * (1.0f / 30.0f);
            mx = fmaxf(mx, lg[e]);
        }
        float den = 0.f, ex[4];
        #pragma unroll
        for (int e = 0; e < 4; ++e) { ex[e] = expf(lg[e] - mx); den += ex[e]; }
        #pragma unroll
        for (int e = 0; e < 4; ++e) routing[b * 4 + e] = ex[e] / den;
    }
}

// ---------------- 3) mix: wmix[b][c][lane] = sum_e r[b][e] * convT[e][c][lane] (32B/thread) ----------------
// affinity: b's 72 blocks run on XCD b>>2, so wmix lines are local-dirty for conv_mfma.
__global__ void mix_kernel(const __hip_bfloat16* __restrict__ convT,
                           const float* __restrict__ routing,
                           __hip_bfloat16* __restrict__ wmix) {
    int blk = blockIdx.x, tid = threadIdx.x;       // 2304 blocks
    int q = blk & 7, j = blk >> 3;                 // j < 288 = 4 b x 72
    int bl = j / 72;
    int b = q * 4 + bl;
    int jj = j - bl * 72;
    int pair = jj * 256 + tid;                     // [0, 18432) pairs within b
    float r0 = routing[b * 4 + 0], r1 = routing[b * 4 + 1];
    float r2 = routing[b * 4 + 2], r3 = routing[b * 4 + 3];
    const size_t ES = (size_t)NCHUNK * 64 * 8;     // 294912 elems per expert
    const __hip_bfloat16* sp = convT + (size_t)pair * 16;
    __hip_bfloat16 o[16];
    #pragma unroll
    for (int h = 0; h < 2; ++h) {
        bf16x8 w0 = *(const bf16x8*)(sp + h * 8);
        bf16x8 w1v = *(const bf16x8*)(sp + h * 8 + ES);
        bf16x8 w2v = *(const bf16x8*)(sp + h * 8 + 2 * ES);
        bf16x8 w3v = *(const bf16x8*)(sp + h * 8 + 3 * ES);
        #pragma unroll
        for (int k = 0; k < 8; ++k) {
            float v = r0 * (float)w0[k] + r1 * (float)w1v[k]
                    + r2 * (float)w2v[k] + r3 * (float)w3v[k];
            o[h * 8 + k] = __float2bfloat16(v);
        }
    }
    uint4* d = (uint4*)(wmix + ((size_t)b * 18432 + pair) * 16);
    d[0] = ((uint4*)o)[0];
    d[1] = ((uint4*)o)[1];
}

// ---------------- 4) dynamic conv: och-partitioned waves (no L2 weight duplication) ----------------
// Wave w owns och rows [w*32, w*32+32) and ALL 8 y rows. Weight slices are disjoint
// across waves (halves the 1.05 GB/launch L2 weight stream); x-row fragments now come
// 10-deep per wave from LDS, where cross-wave duplication is cheap.
#define XSTRIDE 136   // 128 ch + 8 pad elems (16B-aligned rows)
__global__ __launch_bounds__(256, 2)
void conv_mfma(const __hip_bfloat16* __restrict__ xT,
               const __hip_bfloat16* __restrict__ wmix,
               float* __restrict__ out) {
    __shared__ __align__(16) __hip_bfloat16 xs[180 * XSTRIDE];   // 48.96 KB

    // XCD-aware bijective swizzle (1792 % 8 == 0): XCD k owns 4 contiguous b's
    int lin = blockIdx.x;
    int wg  = (lin & 7) * 224 + (lin >> 3);
    int b   = wg / 56;
    int rr  = wg - b * 56;
    int mtile = rr / 28;
    int tile  = rr - mtile * 28;

    const int yt = tile >> 2, xt = tile & 3;
    const int y0 = yt * 8, x0 = xt * 16;
    const int tid = threadIdx.x;
    const int lane = tid & 63, wave = tid >> 6;
    const int wm = wave >> 1;          // och 64-half
    const int mh = wave & 1;           // och 32-quarter within half (mt = mh*2 + mtl)
    const int col = lane & 15, quad = lane >> 4;

    const __hip_bfloat16* xb = xT + (size_t)b * HW * CIN;
    const __hip_bfloat16* wptr = wmix +
        ((size_t)(b * NCHUNK + mtile * 288 + wm)) * 512 + lane * 8;

    // ---- stage full x halo tile (180 px x 128 ch) once ----
    #pragma unroll
    for (int j = 0; j < 12; ++j) {
        int tt = tid + j * 256;
        if (tt < 2880) {                       // 180 px * 16 segs
            int pix = tt >> 4, seg = tt & 15;
            int py = pix / 18, px = pix - py * 18;
            int gy = y0 - 1 + py, gx = x0 - 1 + px;
            uint4 v = {0u, 0u, 0u, 0u};
            if ((unsigned)gy < 56u && (unsigned)gx < 56u)
                v = *(const uint4*)(xb + ((size_t)(gy * 56 + gx) * CIN + seg * 8));
            *(uint4*)(&xs[pix * XSTRIDE + seg * 8]) = v;
        }
    }

    floatx4 acc[2][8];                 // [mtl][nt]: 32 och x 8 y x 16 x per wave
    #pragma unroll
    for (int mtl = 0; mtl < 2; ++mtl)
        #pragma unroll
        for (int nt = 0; nt < 8; ++nt)
            acc[mtl][nt] = (floatx4){0.f, 0.f, 0.f, 0.f};

    bf16x8 af[4][2];    // weight fragments: rotating, prefetch distance 3 (disjoint per wave)
    bf16x8 bfr[2][10];  // 10 row-fragments per (cc,ks,kx) group, double-buffered

    // u = g*3 + ky ; g = cc*6 + ks*3 + kx
    auto lda = [&](int u, bf16x8* dst) {
        const int g = u / 3, ky = u - g * 3;
        const int cc = g / 6, r6 = g - cc * 6;
        const int ks = r6 / 3, kx = r6 - ks * 3;
        const int pp = ky * 3 + kx;
        #pragma unroll
        for (int mtl = 0; mtl < 2; ++mtl)
            dst[mtl] = *(const bf16x8*)(wptr +
                (size_t)(pp * 32 + cc * 16 + ks * 8 + (mh * 2 + mtl) * 2) * 512);
    };
    auto ldb = [&](int g, bf16x8* dst) {
        const int cc = g / 6, r6 = g - cc * 6;
        const int ks = r6 / 3, kx = r6 - ks * 3;
        const int base = cc * 64 + ks * 32 + quad * 8;
        #pragma unroll
        for (int r = 0; r < 10; ++r)
            dst[r] = *(const bf16x8*)(&xs[(r * 18 + col + kx) * XSTRIDE + base]);
    };

    lda(0, af[0]); lda(1, af[1]); lda(2, af[2]);
    __syncthreads();                          // xs visible (the only barrier)
    ldb(0, bfr[0]);

    #pragma unroll
    for (int g = 0; g < 12; ++g) {
        if (g + 1 < 12) ldb(g + 1, bfr[(g + 1) & 1]);
        #pragma unroll
        for (int ky = 0; ky < 3; ++ky) {
            const int u = g * 3 + ky;
            if (u + 3 < 36) lda(u + 3, af[(u + 3) & 3]);
            __builtin_amdgcn_s_setprio(1);
            #pragma unroll
            for (int mtl = 0; mtl < 2; ++mtl)
                #pragma unroll
                for (int nt = 0; nt < 8; ++nt)
                    acc[mtl][nt] = __builtin_amdgcn_mfma_f32_16x16x32_bf16(
                        af[u & 3][mtl], bfr[g & 1][nt + ky], acc[mtl][nt], 0, 0, 0);
            __builtin_amdgcn_s_setprio(0);
        }
    }

    // epilogue: C/D layout col=lane&15, row=quad*4+reg; PLAIN stores (r12 lesson:
    // nontemporal scalar stores defeat L2 write-combining: WRITE 102->134MB, conv +43us)
    const int x = x0 + col;
    if (x < 56) {
        #pragma unroll
        for (int mtl = 0; mtl < 2; ++mtl) {
            int o = mtile * 128 + wave * 32 + mtl * 16 + quad * 4;
            #pragma unroll
            for (int nt = 0; nt < 8; ++nt) {
                int y = y0 + nt;
                float* op = out + (((size_t)b * COUT + o) * 56 + y) * 56 + x;
                #pragma unroll
                for (int r = 0; r < 4; ++r)
                    op[(size_t)r * HW] = acc[mtl][nt][r];
            }
        }
    }
}

extern "C" void kernel_launch(void* const* d_in, const int* in_sizes, int n_in,
                              void* d_out, int out_size, void* d_ws, size_t ws_size,
                              hipStream_t stream) {
    const float* x     = (const float*)d_in[0];
    const float* convs = (const float*)d_in[1];
    const float* w1    = (const float*)d_in[2];
    const float* b1    = (const float*)d_in[3];
    const float* w2    = (const float*)d_in[4];
    const float* b2    = (const float*)d_in[5];
    float* out = (float*)d_out;

    char* ws = (char*)d_ws;
    float* routing       = (float*)(ws + 16384);                        // 512 B
    __hip_bfloat16* xT   = (__hip_bfloat16*)(ws + 16896);               // 25690112 B
    __hip_bfloat16* wmix = (__hip_bfloat16*)(ws + 16896 + 25690112);    // 18874368 B
    __hip_bfloat16* convT= (__hip_bfloat16*)(ws + 16896 + 25690112 + 18874368); // 2359296 B
    // GAP partials alias the wmix region: written by xpose_wswz, read by router,
    // and only then is wmix produced by mix_kernel (stream-serial => safe).
    float* gpart = (float*)wmix;                                        // 802816 B used

    xpose_wswz   <<<3392, 256, 0, stream>>>(x, xT, gpart, convs, convT);
    router_kernel<<<32, 128, 0, stream>>>(gpart, w1, b1, w2, b2, routing);
    mix_kernel   <<<2304, 256, 0, stream>>>(convT, routing, wmix);
    conv_mfma    <<<1792, 256, 0, stream>>>(xT, wmix, out);
}